// Round 1
// baseline (10503.290 us; speedup 1.0000x reference)
//
#include <hip/hip_runtime.h>
#include <math.h>

// NeighborAttentionV2 — Round 1: fully-fused fp32 edge kernel + node GEMM.
// Strategy: fp32 vector (no fp32 MFMA on CDNA4) — compute-bound ~2ms floor.
// Softmax: skip segment_max (attend = exp(l)/sum exp(l) is exact; |l| < ~1 here).
// Aggregation via fp32 atomics into ws: num[N][128], den[N][4].

#define NH 128      // num_hidden
#define NI 256      // num_in (h_E feature dim)
#define HEADS 4
#define TE 16       // edges per block
#define TN 16       // nodes per block (kernel 2)
#define SE (NI + 4) // 260: LDS stride, 16B-aligned rows (260*4=1040=65*16), <=2-way bank alias
#define SH (NH + 4) // 132: 528 bytes, 16B aligned

__device__ __forceinline__ float gelu_f(float x) {
    // exact erf GELU (torch/jax approximate=False)
    return 0.5f * x * (1.0f + erff(x * 0.70710678118654752f));
}

__global__ __launch_bounds__(256, 3) void edge_kernel(
    const float* __restrict__ hV, const float* __restrict__ hE,
    const int* __restrict__ cid_g,
    const float* __restrict__ Wv1, const float* __restrict__ bv1,
    const float* __restrict__ Wv2, const float* __restrict__ bv2,
    const float* __restrict__ Wv3, const float* __restrict__ bv3,
    const float* __restrict__ Wm1, const float* __restrict__ bm1,
    const float* __restrict__ Wm2, const float* __restrict__ bm2,
    const float* __restrict__ Wm3, const float* __restrict__ bm3,
    float* __restrict__ num, float* __restrict__ den)
{
    __shared__ float xe[TE][SE];   // h_E tile (kept live for v-branch)
    __shared__ float xv[TE][SH];   // h_V gather; later v1
    __shared__ float a1[TE][SE];   // m-layer1 out (256); later unused
    __shared__ float b2[TE][SH];   // m-layer2 out (128); later v2
    __shared__ float lg[TE][HEADS];// exp(logits)
    __shared__ int   cid[TE];

    const int t  = threadIdx.x;
    const int e0 = blockIdx.x * TE;

    if (t < TE) cid[t] = cid_g[e0 + t];
    // stage h_E tile: 16 edges x 256 f32 = 1024 float4, 4/thread, coalesced
    {
        const float4* src = (const float4*)(hE + (size_t)e0 * NI);
        #pragma unroll
        for (int i = 0; i < 4; ++i) {
            int idx = t + 256 * i;
            int e = idx >> 6, c4 = idx & 63;
            float4 v = src[(size_t)e * 64 + c4];
            *(float4*)&xe[e][c4 * 4] = v;
        }
    }
    __syncthreads();   // cid visible
    // gather h_V[center]: 512 float4, 2/thread (rows L2/L3-resident: hV = 25.6MB)
    {
        #pragma unroll
        for (int i = 0; i < 2; ++i) {
            int idx = t + 256 * i;
            int e = idx >> 5, c4 = idx & 31;
            const float4* row = (const float4*)(hV + (size_t)cid[e] * NH);
            *(float4*)&xv[e][c4 * 4] = row[c4];
        }
    }
    __syncthreads();

    // ---- m-branch layer 1: [16,384] @ Wm1[256,384]^T -> a1[16,256], gelu ----
    // thread tile: 2 edges x 8 neurons. eg = t&7 keeps each wave on a distinct
    // 64-row slice of Wm1 (weights read exactly once per block).
    {
        const int eg = t & 7, jg = t >> 3;       // jg in [0,32), j = jg*8+jj
        const int ea = eg * 2, eb = ea + 1;
        float acc[2][8];
        #pragma unroll
        for (int jj = 0; jj < 8; ++jj) {
            float b = bm1[jg * 8 + jj];
            acc[0][jj] = b; acc[1][jj] = b;
        }
        for (int k = 0; k < NH; k += 4) {        // K-part 1: h_V columns 0..127
            float4 xa = *(const float4*)&xv[ea][k];
            float4 xb = *(const float4*)&xv[eb][k];
            #pragma unroll
            for (int jj = 0; jj < 8; ++jj) {
                const float4 w = *(const float4*)&Wm1[(size_t)(jg * 8 + jj) * 384 + k];
                acc[0][jj] += xa.x*w.x + xa.y*w.y + xa.z*w.z + xa.w*w.w;
                acc[1][jj] += xb.x*w.x + xb.y*w.y + xb.z*w.z + xb.w*w.w;
            }
        }
        for (int k = 0; k < NI; k += 4) {        // K-part 2: h_E columns 128..383
            float4 xa = *(const float4*)&xe[ea][k];
            float4 xb = *(const float4*)&xe[eb][k];
            #pragma unroll
            for (int jj = 0; jj < 8; ++jj) {
                const float4 w = *(const float4*)&Wm1[(size_t)(jg * 8 + jj) * 384 + 128 + k];
                acc[0][jj] += xa.x*w.x + xa.y*w.y + xa.z*w.z + xa.w*w.w;
                acc[1][jj] += xb.x*w.x + xb.y*w.y + xb.z*w.z + xb.w*w.w;
            }
        }
        #pragma unroll
        for (int jj = 0; jj < 8; ++jj) {
            a1[ea][jg * 8 + jj] = gelu_f(acc[0][jj]);
            a1[eb][jg * 8 + jj] = gelu_f(acc[1][jj]);
        }
    }
    __syncthreads();

    // ---- m-branch layer 2: a1[16,256] @ Wm2[128,256]^T -> b2[16,128], gelu ----
    {
        const int eg = t & 7, jg = t >> 3;       // j = jg*4+jj
        const int ea = eg * 2, eb = ea + 1;
        float acc[2][4];
        #pragma unroll
        for (int jj = 0; jj < 4; ++jj) {
            float b = bm2[jg * 4 + jj];
            acc[0][jj] = b; acc[1][jj] = b;
        }
        for (int k = 0; k < NI; k += 4) {
            float4 xa = *(const float4*)&a1[ea][k];
            float4 xb = *(const float4*)&a1[eb][k];
            #pragma unroll
            for (int jj = 0; jj < 4; ++jj) {
                const float4 w = *(const float4*)&Wm2[(size_t)(jg * 4 + jj) * 256 + k];
                acc[0][jj] += xa.x*w.x + xa.y*w.y + xa.z*w.z + xa.w*w.w;
                acc[1][jj] += xb.x*w.x + xb.y*w.y + xb.z*w.z + xb.w*w.w;
            }
        }
        #pragma unroll
        for (int jj = 0; jj < 4; ++jj) {
            b2[ea][jg * 4 + jj] = gelu_f(acc[0][jj]);
            b2[eb][jg * 4 + jj] = gelu_f(acc[1][jj]);
        }
    }
    __syncthreads();

    // ---- m-branch layer 3 + exp + den atomics: b2 @ Wm3[4,128]^T ----
    if (t < TE * HEADS) {
        int e = t & 15, h = t >> 4;
        float acc = bm3[h];
        for (int k = 0; k < NH; k += 4) {
            float4 x = *(const float4*)&b2[e][k];
            const float4 w = *(const float4*)&Wm3[(size_t)h * 128 + k];
            acc += x.x*w.x + x.y*w.y + x.z*w.z + x.w*w.w;
        }
        float ex = expf(acc * 0.17677669529663687f);   // / sqrt(32)
        lg[e][h] = ex;
        atomicAdd(&den[(size_t)cid[e] * HEADS + h], ex);
    }
    __syncthreads();

    // ---- v-branch layer 1: xe[16,256] @ Wv1[128,256]^T -> xv (reuse), gelu ----
    {
        const int eg = t & 7, jg = t >> 3;
        const int ea = eg * 2, eb = ea + 1;
        float acc[2][4];
        #pragma unroll
        for (int jj = 0; jj < 4; ++jj) {
            float b = bv1[jg * 4 + jj];
            acc[0][jj] = b; acc[1][jj] = b;
        }
        for (int k = 0; k < NI; k += 4) {
            float4 xa = *(const float4*)&xe[ea][k];
            float4 xb = *(const float4*)&xe[eb][k];
            #pragma unroll
            for (int jj = 0; jj < 4; ++jj) {
                const float4 w = *(const float4*)&Wv1[(size_t)(jg * 4 + jj) * 256 + k];
                acc[0][jj] += xa.x*w.x + xa.y*w.y + xa.z*w.z + xa.w*w.w;
                acc[1][jj] += xb.x*w.x + xb.y*w.y + xb.z*w.z + xb.w*w.w;
            }
        }
        #pragma unroll
        for (int jj = 0; jj < 4; ++jj) {
            xv[ea][jg * 4 + jj] = gelu_f(acc[0][jj]);
            xv[eb][jg * 4 + jj] = gelu_f(acc[1][jj]);
        }
    }
    __syncthreads();

    // ---- v-branch layer 2: xv[16,128] @ Wv2[128,128]^T -> b2 (reuse), gelu ----
    {
        const int eg = t & 7, jg = t >> 3;
        const int ea = eg * 2, eb = ea + 1;
        float acc[2][4];
        #pragma unroll
        for (int jj = 0; jj < 4; ++jj) {
            float b = bv2[jg * 4 + jj];
            acc[0][jj] = b; acc[1][jj] = b;
        }
        for (int k = 0; k < NH; k += 4) {
            float4 xa = *(const float4*)&xv[ea][k];
            float4 xb = *(const float4*)&xv[eb][k];
            #pragma unroll
            for (int jj = 0; jj < 4; ++jj) {
                const float4 w = *(const float4*)&Wv2[(size_t)(jg * 4 + jj) * 128 + k];
                acc[0][jj] += xa.x*w.x + xa.y*w.y + xa.z*w.z + xa.w*w.w;
                acc[1][jj] += xb.x*w.x + xb.y*w.y + xb.z*w.z + xb.w*w.w;
            }
        }
        #pragma unroll
        for (int jj = 0; jj < 4; ++jj) {
            b2[ea][jg * 4 + jj] = gelu_f(acc[0][jj]);
            b2[eb][jg * 4 + jj] = gelu_f(acc[1][jj]);
        }
    }
    __syncthreads();

    // ---- v-branch layer 3 (no gelu) + weighted scatter: num += exp(l)*V ----
    {
        const int eg = t & 7, jg = t >> 3;
        const int ea = eg * 2, eb = ea + 1;
        float acc[2][4];
        #pragma unroll
        for (int jj = 0; jj < 4; ++jj) {
            float b = bv3[jg * 4 + jj];
            acc[0][jj] = b; acc[1][jj] = b;
        }
        for (int k = 0; k < NH; k += 4) {
            float4 xa = *(const float4*)&b2[ea][k];
            float4 xb = *(const float4*)&b2[eb][k];
            #pragma unroll
            for (int jj = 0; jj < 4; ++jj) {
                const float4 w = *(const float4*)&Wv3[(size_t)(jg * 4 + jj) * 128 + k];
                acc[0][jj] += xa.x*w.x + xa.y*w.y + xa.z*w.z + xa.w*w.w;
                acc[1][jj] += xb.x*w.x + xb.y*w.y + xb.z*w.z + xb.w*w.w;
            }
        }
        #pragma unroll
        for (int x = 0; x < 2; ++x) {
            int e = ea + x;
            size_t nbase = (size_t)cid[e] * NH;
            #pragma unroll
            for (int jj = 0; jj < 4; ++jj) {
                int j = jg * 4 + jj;
                atomicAdd(&num[nbase + j], lg[e][j >> 5] * acc[x][jj]);
            }
        }
    }
}

// out[n] = (num[n]/den[n,broadcast]) @ Wo^T
__global__ __launch_bounds__(256) void node_kernel(
    const float* __restrict__ num, const float* __restrict__ den,
    const float* __restrict__ Wo, float* __restrict__ out)
{
    __shared__ float agg[TN][SH];
    const int t  = threadIdx.x;
    const int n0 = blockIdx.x * TN;

    #pragma unroll
    for (int i = 0; i < 2; ++i) {
        int idx = t + 256 * i;                 // 0..511
        int nl = idx >> 5, c4 = idx & 31;
        int n = n0 + nl;
        float4 v = *(const float4*)&num[(size_t)n * NH + c4 * 4];
        float d = den[(size_t)n * HEADS + (c4 >> 3)];
        float r = (d != 0.0f) ? 1.0f / d : 0.0f;  // empty-segment guard
        v.x *= r; v.y *= r; v.z *= r; v.w *= r;
        *(float4*)&agg[nl][c4 * 4] = v;
    }
    __syncthreads();

    const int ng = t & 7, jg = t >> 3;          // 2 nodes x 4 outputs
    const int na = ng * 2, nb = na + 1;
    float acc[2][4] = {};
    for (int k = 0; k < NH; k += 4) {
        float4 xa = *(const float4*)&agg[na][k];
        float4 xb = *(const float4*)&agg[nb][k];
        #pragma unroll
        for (int jj = 0; jj < 4; ++jj) {
            const float4 w = *(const float4*)&Wo[(size_t)(jg * 4 + jj) * 128 + k];
            acc[0][jj] += xa.x*w.x + xa.y*w.y + xa.z*w.z + xa.w*w.w;
            acc[1][jj] += xb.x*w.x + xb.y*w.y + xb.z*w.z + xb.w*w.w;
        }
    }
    #pragma unroll
    for (int jj = 0; jj < 4; ++jj) {
        out[(size_t)(n0 + na) * NH + jg * 4 + jj] = acc[0][jj];
        out[(size_t)(n0 + nb) * NH + jg * 4 + jj] = acc[1][jj];
    }
}

extern "C" void kernel_launch(void* const* d_in, const int* in_sizes, int n_in,
                              void* d_out, int out_size, void* d_ws, size_t ws_size,
                              hipStream_t stream) {
    const float* hV  = (const float*)d_in[0];
    const float* hE  = (const float*)d_in[1];
    const int*   cid = (const int*)  d_in[2];
    const float* Wv1 = (const float*)d_in[3];
    const float* bv1 = (const float*)d_in[4];
    const float* Wv2 = (const float*)d_in[5];
    const float* bv2 = (const float*)d_in[6];
    const float* Wv3 = (const float*)d_in[7];
    const float* bv3 = (const float*)d_in[8];
    const float* Wm1 = (const float*)d_in[9];
    const float* bm1 = (const float*)d_in[10];
    const float* Wm2 = (const float*)d_in[11];
    const float* bm2 = (const float*)d_in[12];
    const float* Wm3 = (const float*)d_in[13];
    const float* bm3 = (const float*)d_in[14];
    const float* Wo  = (const float*)d_in[15];

    const int N = in_sizes[0] / NH;   // 50000
    const int E = in_sizes[1] / NI;   // 800000 (divisible by TE)

    float* num = (float*)d_ws;                    // [N][128]
    float* den = num + (size_t)N * NH;            // [N][4]

    hipMemsetAsync(d_ws, 0, (size_t)N * (NH + HEADS) * sizeof(float), stream);
    edge_kernel<<<E / TE, 256, 0, stream>>>(hV, hE, cid,
        Wv1, bv1, Wv2, bv2, Wv3, bv3, Wm1, bm1, Wm2, bm2, Wm3, bm3, num, den);
    node_kernel<<<N / TN, 256, 0, stream>>>(num, den, Wo, (float*)d_out);
}